// Round 1
// baseline (76.860 us; speedup 1.0000x reference)
//
#include <hip/hip_runtime.h>

#define QLEN 1024
#define KLEN 1024
#define BSZ 2
#define NHEAD 16
#define DHEAD 64
#define SCALEF 0.125f
#define BLK_I 64
#define BLK_J 64

typedef __attribute__((ext_vector_type(8))) short s16x8;
typedef __attribute__((ext_vector_type(4))) float f32x4;
typedef __attribute__((ext_vector_type(8))) unsigned short u16x8;

__device__ __forceinline__ unsigned short f2bf(float f) {
    union { float f; unsigned int u; } x; x.f = f;
    unsigned int r = x.u + 0x7fffu + ((x.u >> 16) & 1u);
    return (unsigned short)(r >> 16);
}

// LDS row pads: 72 bf16 elems = 144B = 9 16B-quads -> (row*9 + chunk) % 8
// spreads 16 lanes over all 8 bank-quads (2-way = free).
#define QPAD 72
#define KPAD 72
#define VPAD 72
#define PPAD 72

__global__ __launch_bounds__(256, 2)
void relattn_kernel(const float* __restrict__ q,
                    const float* __restrict__ kh,
                    const float* __restrict__ v,
                    const float* __restrict__ kr,
                    const float* __restrict__ segemb,
                    const float* __restrict__ segmat,
                    const float* __restrict__ rwb,
                    const float* __restrict__ rrb,
                    const float* __restrict__ rsb,
                    const float* __restrict__ mask,
                    float* __restrict__ out)
{
    __shared__ unsigned short QwL[BLK_I][QPAD];
    __shared__ unsigned short QrL[BLK_I][QPAD];
    __shared__ unsigned short KhL[BLK_J][KPAD];
    __shared__ unsigned short KrL[BLK_J][KPAD];
    __shared__ unsigned short VtL[DHEAD][VPAD];   // transposed: [d][j]
    __shared__ unsigned short PlL[4][16][PPAD];   // per-wave P tile
    __shared__ float ef0s[BLK_I][2];

    const int i0   = blockIdx.x * BLK_I;
    const int b    = blockIdx.y;
    const int n    = blockIdx.z;
    const int tid  = threadIdx.x;
    const int wave = tid >> 6;
    const int lane = tid & 63;
    const int q4   = lane >> 4;
    const int c    = lane & 15;
    const int RS   = BSZ * NHEAD * DHEAD;          // 2048 floats per seq row
    const int boff = b * NHEAD * DHEAD + n * DHEAD;

    // ---- stage Qw = q + r_w_bias, Qr = q + r_r_bias (bf16) ----
    {
        const int il = tid >> 2;
        const int dc = (tid & 3) * 16;
        const float* qp = q + (size_t)(i0 + il) * RS + boff + dc;
        float qv[16], wb[16], rb[16];
#pragma unroll
        for (int e = 0; e < 4; ++e) {
            *(f32x4*)&qv[e*4] = *(const f32x4*)(qp + e*4);
            *(f32x4*)&wb[e*4] = *(const f32x4*)(rwb + n*DHEAD + dc + e*4);
            *(f32x4*)&rb[e*4] = *(const f32x4*)(rrb + n*DHEAD + dc + e*4);
        }
        u16x8 w0, w1, r0, r1;
#pragma unroll
        for (int e = 0; e < 8; ++e) {
            w0[e] = f2bf(qv[e]   + wb[e]);
            w1[e] = f2bf(qv[e+8] + wb[e+8]);
            r0[e] = f2bf(qv[e]   + rb[e]);
            r1[e] = f2bf(qv[e+8] + rb[e+8]);
        }
        *(u16x8*)&QwL[il][dc]     = w0;
        *(u16x8*)&QwL[il][dc + 8] = w1;
        *(u16x8*)&QrL[il][dc]     = r0;
        *(u16x8*)&QrL[il][dc + 8] = r1;
    }
    // ---- ef0[i][s] = sum_d (q + r_s_bias) * seg_embed[s] ----
    if (tid < 2 * BLK_I) {
        const int il = tid >> 1;
        const int s  = tid & 1;
        const float* qp = q + (size_t)(i0 + il) * RS + boff;
        const float* se = segemb + (s * NHEAD + n) * DHEAD;
        const float* rs = rsb + n * DHEAD;
        float acc = 0.f;
#pragma unroll
        for (int d = 0; d < DHEAD; ++d) acc += (qp[d] + rs[d]) * se[d];
        ef0s[il][s] = acc;
    }
    __syncthreads();

    // ---- persistent per-lane state ----
    s16x8 qwf[2], qrf[2];
#pragma unroll
    for (int kk = 0; kk < 2; ++kk) {
        qwf[kk] = *(const s16x8*)&QwL[wave*16 + c][kk*32 + q4*8];
        qrf[kk] = *(const s16x8*)&QrL[wave*16 + c][kk*32 + q4*8];
    }
    float e0[4], e1[4];
    int ig[4];
#pragma unroll
    for (int r = 0; r < 4; ++r) {
        const int iloc = wave*16 + q4*4 + r;
        ig[r] = i0 + iloc;
        e0[r] = ef0s[iloc][0];
        e1[r] = ef0s[iloc][1];
    }

    float m[4], lsum[4];
    f32x4 acc[4];
#pragma unroll
    for (int r = 0; r < 4; ++r) { m[r] = -INFINITY; lsum[r] = 0.f; }
#pragma unroll
    for (int dt = 0; dt < 4; ++dt) acc[dt] = (f32x4)0.f;

    for (int jt = 0; jt < KLEN / BLK_J; ++jt) {
        const int j0 = jt * BLK_J;
        // ---- stage Kh, Kr(+1 shift), V^T ----
#pragma unroll
        for (int half = 0; half < 2; ++half) {
            const int cid = tid + half * 256;
            const int jl  = cid >> 3;
            const int d0  = (cid & 7) * 8;
            const float* khp = kh + (size_t)(j0 + jl) * RS + boff + d0;
            const float* krp = kr + (size_t)(j0 + jl + 1) * RS + boff + d0; // rel_shift: +1
            const float* vp  = v  + (size_t)(j0 + jl) * RS + boff + d0;
            float hv[8], rv[8], vv[8];
            *(f32x4*)&hv[0] = *(const f32x4*)(khp);
            *(f32x4*)&hv[4] = *(const f32x4*)(khp + 4);
            *(f32x4*)&rv[0] = *(const f32x4*)(krp);
            *(f32x4*)&rv[4] = *(const f32x4*)(krp + 4);
            *(f32x4*)&vv[0] = *(const f32x4*)(vp);
            *(f32x4*)&vv[4] = *(const f32x4*)(vp + 4);
            u16x8 hb, rb2;
#pragma unroll
            for (int e = 0; e < 8; ++e) { hb[e] = f2bf(hv[e]); rb2[e] = f2bf(rv[e]); }
            *(u16x8*)&KhL[jl][d0] = hb;
            *(u16x8*)&KrL[jl][d0] = rb2;
#pragma unroll
            for (int e = 0; e < 8; ++e) VtL[d0 + e][jl] = f2bf(vv[e]);
        }
        __syncthreads();

        // ---- S = Qw*Kh^T + Qr*Kr^T  (4 j-subtiles of 16) ----
        f32x4 s[4];
#pragma unroll
        for (int js = 0; js < 4; ++js) s[js] = (f32x4)0.f;
#pragma unroll
        for (int kk = 0; kk < 2; ++kk) {
#pragma unroll
            for (int js = 0; js < 4; ++js) {
                const s16x8 khf = *(const s16x8*)&KhL[js*16 + c][kk*32 + q4*8];
                const s16x8 krf = *(const s16x8*)&KrL[js*16 + c][kk*32 + q4*8];
                s[js] = __builtin_amdgcn_mfma_f32_16x16x32_bf16(qwf[kk], khf, s[js], 0, 0, 0);
                s[js] = __builtin_amdgcn_mfma_f32_16x16x32_bf16(qrf[kk], krf, s[js], 0, 0, 0);
            }
        }

        // ---- + ef + mask, scale; online softmax ----
        float mt[4];
#pragma unroll
        for (int r = 0; r < 4; ++r) {
#pragma unroll
            for (int js = 0; js < 4; ++js) {
                const int jg = j0 + js*16 + c;
                const size_t sij = (size_t)ig[r] * KLEN + jg;
                const float2 sm = *(const float2*)(segmat + sij * (BSZ*2) + b*2);
                const float mk = mask[sij];
                s[js][r] = (s[js][r] + sm.x*e0[r] + sm.y*e1[r]) * SCALEF - 1e30f * mk;
            }
            mt[r] = fmaxf(fmaxf(s[0][r], s[1][r]), fmaxf(s[2][r], s[3][r]));
        }
#pragma unroll
        for (int xm = 1; xm <= 8; xm <<= 1) {
#pragma unroll
            for (int r = 0; r < 4; ++r)
                mt[r] = fmaxf(mt[r], __shfl_xor(mt[r], xm, 64));
        }
#pragma unroll
        for (int r = 0; r < 4; ++r) {
            const float mn = fmaxf(m[r], mt[r]);
            const float sc = __expf(m[r] - mn);
            m[r] = mn;
            lsum[r] *= sc;
#pragma unroll
            for (int dt = 0; dt < 4; ++dt) acc[dt][r] *= sc;
            float ps = 0.f;
#pragma unroll
            for (int js = 0; js < 4; ++js) {
                const float p = __expf(s[js][r] - mn);
                ps += p;
                PlL[wave][q4*4 + r][js*16 + c] = f2bf(p);
            }
#pragma unroll
            for (int xm = 1; xm <= 8; xm <<= 1) ps += __shfl_xor(ps, xm, 64);
            lsum[r] += ps;
        }

        // ---- PV: acc += P * V ----
#pragma unroll
        for (int kk = 0; kk < 2; ++kk) {
            const s16x8 pf = *(const s16x8*)&PlL[wave][c][kk*32 + q4*8];
#pragma unroll
            for (int dt = 0; dt < 4; ++dt) {
                const s16x8 vf = *(const s16x8*)&VtL[dt*16 + c][kk*32 + q4*8];
                acc[dt] = __builtin_amdgcn_mfma_f32_16x16x32_bf16(pf, vf, acc[dt], 0, 0, 0);
            }
        }
        __syncthreads();
    }

    // ---- epilogue: normalize and store ----
#pragma unroll
    for (int r = 0; r < 4; ++r) {
        const float inv = 1.f / lsum[r];
        float* op = out + (size_t)ig[r] * RS + boff;
#pragma unroll
        for (int dt = 0; dt < 4; ++dt)
            op[dt*16 + c] = acc[dt][r] * inv;
    }
}

extern "C" void kernel_launch(void* const* d_in, const int* in_sizes, int n_in,
                              void* d_out, int out_size, void* d_ws, size_t ws_size,
                              hipStream_t stream) {
    const float* q   = (const float*)d_in[0];
    const float* kh  = (const float*)d_in[1];
    const float* v   = (const float*)d_in[2];
    const float* kr  = (const float*)d_in[3];
    const float* se  = (const float*)d_in[4];
    const float* sm  = (const float*)d_in[5];
    const float* rwb = (const float*)d_in[6];
    const float* rrb = (const float*)d_in[7];
    const float* rsb = (const float*)d_in[8];
    const float* msk = (const float*)d_in[9];
    float* out = (float*)d_out;
    dim3 grid(QLEN / BLK_I, BSZ, NHEAD);
    relattn_kernel<<<grid, 256, 0, stream>>>(q, kh, v, kr, se, sm, rwb, rrb, rsb, msk, out);
}